// Round 9
// baseline (241.659 us; speedup 1.0000x reference)
//
#include <hip/hip_runtime.h>
#include <stdint.h>

#define NUM_HEADS 16
#define HEAD_DIM 64
#define D_MODEL 1024
#define SEQ 2048
#define BATCH 2

typedef unsigned short u16;
typedef _Float16 f16x8 __attribute__((ext_vector_type(8)));
typedef float f32x4 __attribute__((ext_vector_type(4)));

__device__ __forceinline__ u16 f2h(float f) {
    _Float16 h = (_Float16)f;
    return __builtin_bit_cast(u16, h);
}
__device__ __forceinline__ float h2f(u16 h) {
    return (float)__builtin_bit_cast(_Float16, h);
}
// pack two f32 -> two f16 (RTZ) as a uint32
__device__ __forceinline__ uint32_t pkrtz(float a, float b) {
    return __builtin_bit_cast(uint32_t, __builtin_amdgcn_cvt_pkrtz(a, b));
}
// pack two f32 -> two f16 round-to-nearest (matches reference cast rounding)
__device__ __forceinline__ uint32_t pkrtn(float a, float b) {
    return (uint32_t)f2h(a) | ((uint32_t)f2h(b) << 16);
}

// raw exp2 (v_exp_f32). Q is pre-scaled by log2(e) so this IS exp().
__device__ __forceinline__ float ex2(float x) {
#if __has_builtin(__builtin_amdgcn_exp2f)
    return __builtin_amdgcn_exp2f(x);
#else
    float r;
    asm("v_exp_f32 %0, %1" : "=v"(r) : "v"(x));
    return r;
#endif
}

__device__ __forceinline__ f16x8 ld8h(const u16* p) {
    return *reinterpret_cast<const f16x8*>(p);
}

__device__ __forceinline__ void gl_lds16(const void* g, void* l) {
    __builtin_amdgcn_global_load_lds(
        (const __attribute__((address_space(1))) void*)g,
        (__attribute__((address_space(3))) void*)l,
        16, 0, 0);
}

// ---- DPP 16-lane sum (VALU pipe) ----
template <int CTRL>
__device__ __forceinline__ float dpp_mov(float x) {
    return __builtin_bit_cast(float,
        __builtin_amdgcn_update_dpp(0, __builtin_bit_cast(int, x), CTRL, 0xf, 0xf, true));
}
__device__ __forceinline__ float rowsum16(float x) {
    x += dpp_mov<0x121>(x);
    x += dpp_mov<0x122>(x);
    x += dpp_mov<0x124>(x);
    x += dpp_mov<0x128>(x);
    return x;
}

// ---------------- prep: transpose 3 weights -> fp16 (x-cast now fused into k_proj) ----------------
__global__ __launch_bounds__(256) void k_prep(const float* __restrict__ Wq,
                                              const float* __restrict__ Wkv,
                                              const float* __restrict__ Wp,
                                              u16* __restrict__ WqT16,
                                              u16* __restrict__ WkvT16,
                                              u16* __restrict__ WpT16) {
    __shared__ float tile[32][33];
    const int t = blockIdx.x;              // 0..4095
    const float* W; u16* WT; int N, bi;
    if (t < 1024)      { W = Wq;  WT = WqT16;  N = 1024; bi = t; }
    else if (t < 3072) { W = Wkv; WT = WkvT16; N = 2048; bi = t - 1024; }
    else               { W = Wp;  WT = WpT16;  N = 1024; bi = t - 3072; }
    const int K = 1024;
    const int nb = N / 32;
    const int bn = (bi % nb) * 32, bk = (bi / nb) * 32;
    const int tx = threadIdx.x & 31;
    const int ty = threadIdx.x >> 5;
#pragma unroll
    for (int i = 0; i < 32; i += 8)
        tile[ty + i][tx] = W[(size_t)(bk + ty + i) * N + bn + tx];
    __syncthreads();
#pragma unroll
    for (int i = 0; i < 32; i += 8)
        WT[(size_t)(bn + ty + i) * K + bk + tx] = f2h(tile[tx][ty + i]);
}

// ---------------- fp16 GEMM mainloop, double-buffered (128M x 128N tile) ----------------
__device__ __forceinline__ void gemm_mainloop_f16(const u16* __restrict__ A,
                                                  const u16* __restrict__ Bt,
                                                  u16* As, u16* Bs,
                                                  int tileM, int tileN, int K,
                                                  f32x4 acc[4][4]) {
    const int tid = threadIdx.x;
    const int lane = tid & 63;
    const int wv = tid >> 6;
    const int wm = wv >> 1, wn = wv & 1;
    const int quad = lane >> 4, l15 = lane & 15;

    const int c0 = tid, c1 = tid + 256;
    const u16* Ap0 = A + (size_t)(tileM + (c0 >> 2)) * K + (c0 & 3) * 8;
    const u16* Ap1 = A + (size_t)(tileM + (c1 >> 2)) * K + (c1 & 3) * 8;
    const u16* Bp0 = Bt + (size_t)(tileN + (c0 >> 2)) * K + (c0 & 3) * 8;
    const u16* Bp1 = Bt + (size_t)(tileN + (c1 >> 2)) * K + (c1 & 3) * 8;

    // prologue: stage K-step 0 into buffer 0
    gl_lds16(Ap0, &As[c0 * 8]);
    gl_lds16(Ap1, &As[c1 * 8]);
    gl_lds16(Bp0, &Bs[c0 * 8]);
    gl_lds16(Bp1, &Bs[c1 * 8]);

    for (int k0 = 0; k0 < K; k0 += 32) {
        __syncthreads();
        const int cb = (k0 >> 5) & 1;
        if (k0 + 32 < K) {
            const int nbuf = cb ^ 1;
            gl_lds16(Ap0 + k0 + 32, &As[nbuf * 4096 + c0 * 8]);
            gl_lds16(Ap1 + k0 + 32, &As[nbuf * 4096 + c1 * 8]);
            gl_lds16(Bp0 + k0 + 32, &Bs[nbuf * 4096 + c0 * 8]);
            gl_lds16(Bp1 + k0 + 32, &Bs[nbuf * 4096 + c1 * 8]);
        }
        const int cbo = cb * 4096;
        f16x8 af[4], bfr[4];
#pragma unroll
        for (int mi = 0; mi < 4; ++mi)
            af[mi] = ld8h(&As[cbo + (wm * 64 + mi * 16 + l15) * 32 + quad * 8]);
#pragma unroll
        for (int ni = 0; ni < 4; ++ni)
            bfr[ni] = ld8h(&Bs[cbo + (wn * 64 + ni * 16 + l15) * 32 + quad * 8]);
#pragma unroll
        for (int mi = 0; mi < 4; ++mi)
#pragma unroll
            for (int ni = 0; ni < 4; ++ni)
                acc[mi][ni] = __builtin_amdgcn_mfma_f32_16x16x32_f16(
                    af[mi], bfr[ni], acc[mi][ni], 0, 0, 0);
    }
}

// ---------------- fp32-A GEMM mainloop: stages fp32 x directly, converts (RTN)
// at fragment read. A-tile LDS layout [128 rows][8 chunks-of-4-floats] with
// chunk index XOR (row&7) pre-applied on the GLOBAL source (gl_lds dest must
// stay linear); the fragment read undoes it -> per-bank load = b128 minimum.
__device__ __forceinline__ void gemm_mainloop_f32A(const float* __restrict__ A,
                                                   const u16* __restrict__ Bt,
                                                   float* Asf, u16* Bs,
                                                   int tileM, int tileN, int K,
                                                   f32x4 acc[4][4]) {
    const int tid = threadIdx.x;
    const int lane = tid & 63;
    const int wv = tid >> 6;
    const int wm = wv >> 1, wn = wv & 1;
    const int quad = lane >> 4, l15 = lane & 15;

    const int c0 = tid, c1 = tid + 256;
    const u16* Bp0 = Bt + (size_t)(tileN + (c0 >> 2)) * K + (c0 & 3) * 8;
    const u16* Bp1 = Bt + (size_t)(tileN + (c1 >> 2)) * K + (c1 & 3) * 8;

    // A fp32 staging: slot s = p*256+tid covers (row = s>>3, chunk = s&7);
    // p adds 32 to row (row&7 invariant) so one base pointer serves all 4.
    const int arow = tid >> 3;                       // 0..31
    const int ach = (tid & 7) ^ (arow & 7);          // source chunk XOR-swizzle
    const float* Ap0 = A + (size_t)(tileM + arow) * K + ach * 4;

    // prologue: stage K-step 0 into buffer 0
#pragma unroll
    for (int p = 0; p < 4; ++p)
        gl_lds16(Ap0 + (size_t)p * 32 * K, &Asf[(p * 256 + tid) * 4]);
    gl_lds16(Bp0, &Bs[c0 * 8]);
    gl_lds16(Bp1, &Bs[c1 * 8]);

    for (int k0 = 0; k0 < K; k0 += 32) {
        __syncthreads();
        const int cb = (k0 >> 5) & 1;
        if (k0 + 32 < K) {
            const int nbuf = cb ^ 1;
#pragma unroll
            for (int p = 0; p < 4; ++p)
                gl_lds16(Ap0 + k0 + 32 + (size_t)p * 32 * K,
                         &Asf[nbuf * 4096 + (p * 256 + tid) * 4]);
            gl_lds16(Bp0 + k0 + 32, &Bs[nbuf * 4096 + c0 * 8]);
            gl_lds16(Bp1 + k0 + 32, &Bs[nbuf * 4096 + c1 * 8]);
        }
        const int ao4 = cb * 4096;                   // float index
        const int bo = cb * 4096;                    // u16 index
        f16x8 af[4], bfr[4];
        const int sx = l15 & 7;
#pragma unroll
        for (int mi = 0; mi < 4; ++mi) {
            const int row = wm * 64 + mi * 16 + l15;     // row&7 == l15&7
            float4 cA = *reinterpret_cast<const float4*>(
                &Asf[ao4 + row * 32 + (((quad * 2) ^ sx) * 4)]);
            float4 cB = *reinterpret_cast<const float4*>(
                &Asf[ao4 + row * 32 + (((quad * 2 + 1) ^ sx) * 4)]);
            union { f16x8 v; uint32_t u[4]; } cv;
            cv.u[0] = pkrtn(cA.x, cA.y);             // RTN: cast error identical
            cv.u[1] = pkrtn(cA.z, cA.w);             //      to the old k_prep path
            cv.u[2] = pkrtn(cB.x, cB.y);
            cv.u[3] = pkrtn(cB.z, cB.w);
            af[mi] = cv.v;
        }
#pragma unroll
        for (int ni = 0; ni < 4; ++ni)
            bfr[ni] = ld8h(&Bs[bo + (wn * 64 + ni * 16 + l15) * 32 + quad * 8]);
#pragma unroll
        for (int mi = 0; mi < 4; ++mi)
#pragma unroll
            for (int ni = 0; ni < 4; ++ni)
                acc[mi][ni] = __builtin_amdgcn_mfma_f32_16x16x32_f16(
                    af[mi], bfr[ni], acc[mi][ni], 0, 0, 0);
    }
}

#define ACC_INIT()                                                   \
    f32x4 acc[4][4];                                                 \
    _Pragma("unroll") for (int i = 0; i < 4; ++i)                    \
        _Pragma("unroll") for (int j = 0; j < 4; ++j)                \
            acc[i][j] = (f32x4){0.f, 0.f, 0.f, 0.f};

// ---------------- fused QKV projection (fp32 x read directly; coalesced epilogue) ----------------
__global__ __launch_bounds__(256, 2) void k_proj_f16(const float* __restrict__ xq,
                                                     const float* __restrict__ xc,
                                                     const u16* __restrict__ WqT16,
                                                     const u16* __restrict__ WkvT16,
                                                     const float* __restrict__ lng,
                                                     const float* __restrict__ lnb,
                                                     u16* __restrict__ Qh_h,
                                                     u16* __restrict__ Qh_l,
                                                     u16* __restrict__ Kh,
                                                     u16* __restrict__ VT) {
    __shared__ __align__(16) float Asf[2 * 128 * 32];   // 32 KB fp32 A-tiles
    __shared__ __align__(16) u16 Bs[2 * 128 * 32];      // 16 KB fp16 B-tiles
    const int bx = blockIdx.x;
    const int tileM = blockIdx.y * 128;
    const int tid = threadIdx.x;
    const int lane = tid & 63;
    const int wv = tid >> 6;
    const int wm = wv >> 1, wn = wv & 1;
    const int quad = lane >> 4, l15 = lane & 15;
    ACC_INIT();

    if (bx < 16) {   // Q or K: fp16 GEMM + LayerNorm
        const bool isQ = bx < 8;
        const int tileN = (bx & 7) * 128;
        const float* Axx = isQ ? xq : xc;
        const u16* Bt  = isQ ? WqT16 : WkvT16;
        // Q scale = sqrt(64) * log2(e): softmax runs in exp2 domain. K unscaled.
        const float scl = isQ ? 11.5415603294809528f : 1.0f;

        gemm_mainloop_f32A(Axx, Bt, Asf, Bs, tileM, tileN, D_MODEL, acc);

        float gv[4], bv[4];
#pragma unroll
        for (int ni = 0; ni < 4; ++ni) { gv[ni] = lng[ni * 16 + l15]; bv[ni] = lnb[ni * 16 + l15]; }

        __syncthreads();   // all waves done with Asf/Bs mainloop reads
        // per-wave-private 8KB bounce region (u16[4096])
        u16* reg = (wv < 2 ? reinterpret_cast<u16*>(Asf) : Bs) + (wv & 1) * 4096;
        const int h = (tileN + wn * 64) >> 6;            // uniform per wave
        const int mbase0 = tileM + wm * 64;
        const int bb = mbase0 >> 11;
        const size_t gb0 = (((size_t)bb * NUM_HEADS + h) * SEQ + (mbase0 & (SEQ - 1))) * HEAD_DIM;

#pragma unroll
        for (int mi = 0; mi < 4; ++mi) {
#pragma unroll
            for (int r = 0; r < 4; ++r) {
                float sum = 0.f, sq = 0.f;
#pragma unroll
                for (int ni = 0; ni < 4; ++ni) { float x = acc[mi][ni][r]; sum += x; sq += x * x; }
                sum = rowsum16(sum);
                sq  = rowsum16(sq);
                float mu = sum * (1.f / 64.f);
                float var = sq * (1.f / 64.f) - mu * mu;
                float rs = rsqrtf(var + 1e-5f);
                const int wrow = quad * 4 + r;
#pragma unroll
                for (int ni = 0; ni < 4; ++ni) {
                    float y = ((acc[mi][ni][r] - mu) * rs * gv[ni] + bv[ni]) * scl;
                    u16 yh = f2h(y);
                    reg[wrow * 64 + ni * 16 + l15] = yh;
                    if (isQ) reg[1024 + wrow * 64 + ni * 16 + l15] = f2h(y - h2f(yh));
                }
            }
            // coalesced readback: 2 rounds x 8 rows x 128B = 1KB contiguous/instr
            const size_t gmi = gb0 + (size_t)mi * 16 * 64;
#pragma unroll
            for (int p = 0; p < 2; ++p) {
                const int row = p * 8 + (lane >> 3);
                const int off = (lane & 7) * 8;
                uint4 vh = *reinterpret_cast<const uint4*>(&reg[row * 64 + off]);
                if (isQ) {
                    uint4 vl = *reinterpret_cast<const uint4*>(&reg[1024 + row * 64 + off]);
                    *reinterpret_cast<uint4*>(&Qh_h[gmi + row * 64 + off]) = vh;
                    *reinterpret_cast<uint4*>(&Qh_l[gmi + row * 64 + off]) = vl;
                } else {
                    *reinterpret_cast<uint4*>(&Kh[gmi + row * 64 + off]) = vh;
                }
            }
        }
    } else {         // V: fp16 GEMM, store fp16 transposed (d-major)
        const int tileN = D_MODEL + (bx - 16) * 128;
        gemm_mainloop_f32A(xc, WkvT16, Asf, Bs, tileM, tileN, D_MODEL, acc);

        __syncthreads();   // all waves done with Asf/Bs mainloop reads
        u16* reg = (wv < 2 ? reinterpret_cast<u16*>(Asf) : Bs) + (wv & 1) * 4096;
        // bounce in: per (mi,ni) one 8B LDS write (4 n-values); chunk-pair XOR'd by d
#pragma unroll
        for (int mi = 0; mi < 4; ++mi) {
#pragma unroll
            for (int ni = 0; ni < 4; ++ni) {
                const int d = ni * 16 + l15;
                const int pc = (mi * 2 + (quad >> 1)) ^ (d & 7);
                ushort4 o;
                o.x = f2h(acc[mi][ni][0]);
                o.y = f2h(acc[mi][ni][1]);
                o.z = f2h(acc[mi][ni][2]);
                o.w = f2h(acc[mi][ni][3]);
                *reinterpret_cast<ushort4*>(&reg[d * 64 + pc * 8 + (quad & 1) * 4]) = o;
            }
        }
        const int h = (tileN + wn * 64 - D_MODEL) >> 6;    // uniform per wave
        const int m0 = tileM + wm * 64;
        const int bb = m0 >> 11, n0 = m0 & (SEQ - 1);
        const size_t vbase = (((size_t)bb * NUM_HEADS + h) * HEAD_DIM) * SEQ + n0;
        // readback: 8 rounds x 8 d-rows x 128B transactions
#pragma unroll
        for (int p = 0; p < 8; ++p) {
            const int d = p * 8 + (lane >> 3);
            const int c = lane & 7;
            uint4 v = *reinterpret_cast<const uint4*>(&reg[d * 64 + ((c ^ (d & 7)) * 8)]);
            *reinterpret_cast<uint4*>(&VT[vbase + (size_t)d * SEQ + c * 8]) = v;
        }
    }
}

// ---------------- output projection + bias -> out fp32 (fp16 GEMM) ----------------
__global__ __launch_bounds__(256, 2) void k_gemm_out(const u16* __restrict__ A,
                                                     const u16* __restrict__ Bt,
                                                     const float* __restrict__ bp,
                                                     float* __restrict__ out) {
    __shared__ __align__(16) u16 As[2 * 128 * 32];
    __shared__ __align__(16) u16 Bs[2 * 128 * 32];
    const int tileM = blockIdx.y * 128, tileN = blockIdx.x * 128;
    const int tid = threadIdx.x;
    const int lane = tid & 63;
    const int wv = tid >> 6;
    const int wm = wv >> 1, wn = wv & 1;
    const int quad = lane >> 4, l15 = lane & 15;
    ACC_INIT();
    gemm_mainloop_f16(A, Bt, As, Bs, tileM, tileN, D_MODEL, acc);

    float bpv[4];
#pragma unroll
    for (int ni = 0; ni < 4; ++ni) bpv[ni] = bp[tileN + wn * 64 + ni * 16 + l15];
#pragma unroll
    for (int mi = 0; mi < 4; ++mi) {
#pragma unroll
        for (int r = 0; r < 4; ++r) {
            int m = tileM + wm * 64 + mi * 16 + quad * 4 + r;
#pragma unroll
            for (int ni = 0; ni < 4; ++ni) {
                int colg = tileN + wn * 64 + ni * 16 + l15;
                out[(size_t)m * D_MODEL + colg] = acc[mi][ni][r] + bpv[ni];
            }
        }
    }
}

// ---------------- flash attention v10 (measured best: 82.7-84us): 32q/wave,
// block covers 128 q-rows, grid 512. VGPR 116 natural (NO forced bound).
__global__ __launch_bounds__(256) void k_attn(const u16* __restrict__ Qh_h,
                                              const u16* __restrict__ Qh_l,
                                              const u16* __restrict__ Kh,
                                              const u16* __restrict__ VT,
                                              u16* __restrict__ AO) {
    __shared__ __align__(16) u16 Ks[2 * 64 * 64];   // fp16, double-buffered
    __shared__ __align__(16) u16 Vs[2 * 64 * 64];   // fp16, double-buffered
    __shared__ __align__(16) u16 Ps[128 * 64];      // fp16, chunk+unit XOR swizzled

    const int tid = threadIdx.x;
    const int lane = tid & 63;
    const int wv = tid >> 6;               // wave owns q cols [wv*32, wv*32+32)
    const int quad = lane >> 4, l15 = lane & 15;
    const int sw = l15 & 3;                // Ps chunk XOR key
    const int w1 = (l15 >> 2) & 1;         // Ps 8B-unit XOR key (bank spread)
    const int id = blockIdx.x;             // 0..511
    const int bh = (id & 7) | (((id >> 7) & 3) << 3);  // bh&7 == XCD id
    const int qt = (id >> 3) & 15;         // q-tile of 128 rows

    const size_t bh_off = (size_t)bh * SEQ * HEAD_DIM;
    const u16* Vbh = VT + (size_t)bh * HEAD_DIM * SEQ;

    // Q fragments (B operand), 2 q-halves x 2 k-chunks, split fp16
    f16x8 qfh[2][2], qfl[2][2];
#pragma unroll
    for (int h = 0; h < 2; ++h)
#pragma unroll
        for (int kt = 0; kt < 2; ++kt) {
            size_t off = bh_off +
                (size_t)(qt * 128 + wv * 32 + h * 16 + l15) * HEAD_DIM + kt * 32 + quad * 8;
            qfh[h][kt] = ld8h(Qh_h + off);
            qfl[h][kt] = ld8h(Qh_l + off);
        }

    // all-ones A fragment for the row-sum MFMA (l = sum_k P[k][q])
    f16x8 ones;
#pragma unroll
    for (int i = 0; i < 8; ++i) ones[i] = (_Float16)1.0f;

    // staging pointers (wave stages tile rows [wv*16, wv*16+16))
    const int rr = lane >> 3;
    const int ss = lane & 7;
    const int cc = ss ^ rr;                // XOR chunk swizzle on global source
    const int row0 = wv * 16 + rr;
    const u16* k0 = Kh + bh_off + (size_t)row0 * HEAD_DIM + cc * 8;
    const u16* v0 = Vbh + (size_t)row0 * SEQ + cc * 8;
    const int ldsW = (wv * 16) * 64;       // wave's row base within a buffer

    f32x4 acc_o[2][4];                     // O^T[d][q] per q-half
    f32x4 acc_l0 = (f32x4){0.f, 0.f, 0.f, 0.f};   // only [0] live
    f32x4 acc_l1 = (f32x4){0.f, 0.f, 0.f, 0.f};
    float m0 = -3.0e38f, m1 = -3.0e38f;
#pragma unroll
    for (int h = 0; h < 2; ++h)
#pragma unroll
        for (int ni = 0; ni < 4; ++ni) acc_o[h][ni] = (f32x4){0.f, 0.f, 0.f, 0.f};

    // prologue: stage tile 0 into buffer 0
    gl_lds16(k0,                &Ks[ldsW]);
    gl_lds16(k0 + 8 * HEAD_DIM, &Ks[ldsW + 8 * 64]);
    gl_lds16(v0,                &Vs[ldsW]);
    gl_lds16(v0 + 8 * SEQ,      &Vs[ldsW + 8 * 64]);

    const int psRow0 = (wv * 32 + l15) * 64;         // q-half 0 row (wave-private)
    const int psRow1 = psRow0 + 16 * 64;             // q-half 1 row
    const int psX = (quad ^ (w1 << 1)) * 4;          // unit-XOR'd write offset

    for (int j = 0; j < SEQ / 64; ++j) {
        __syncthreads();   // drains vmcnt -> buf[j&1] ready; all waves done with buf[(j+1)&1]
        if (j + 1 < SEQ / 64) {
            const int nb = (j + 1) & 1;
            const size_t ko = (size_t)(j + 1) * 64 * HEAD_DIM;
            const int vo = (j + 1) * 64;
            gl_lds16(k0 + ko,                &Ks[nb * 4096 + ldsW]);
            gl_lds16(k0 + ko + 8 * HEAD_DIM, &Ks[nb * 4096 + ldsW + 8 * 64]);
            gl_lds16(v0 + vo,                &Vs[nb * 4096 + ldsW]);
            gl_lds16(v0 + vo + 8 * SEQ,      &Vs[nb * 4096 + ldsW + 8 * 64]);
        }
        const int bb = (j & 1) * 4096;

        // --- S^T = K.Q^T (64 keys x 32 q per wave): each kf feeds 4 MFMAs ---
        f32x4 s0[4], s1[4];   // per q-half: col q=l15, row key=ni*16+quad*4+r
#pragma unroll
        for (int ni = 0; ni < 4; ++ni) {
            s0[ni] = (f32x4){0.f, 0.f, 0.f, 0.f};
            s1[ni] = (f32x4){0.f, 0.f, 0.f, 0.f};
        }
#pragma unroll
        for (int kt = 0; kt < 2; ++kt) {
            f16x8 kf[4];
#pragma unroll
            for (int ni = 0; ni < 4; ++ni) {
                int slot = (kt * 4 + quad) ^ (l15 & 7);
                kf[ni] = ld8h(&Ks[bb + (ni * 16 + l15) * 64 + slot * 8]);
            }
#pragma unroll
            for (int ni = 0; ni < 4; ++ni) {
                s0[ni] = __builtin_amdgcn_mfma_f32_16x16x32_f16(
                    kf[ni], qfh[0][kt], s0[ni], 0, 0, 0);
                s0[ni] = __builtin_amdgcn_mfma_f32_16x16x32_f16(
                    kf[ni], qfl[0][kt], s0[ni], 0, 0, 0);
                s1[ni] = __builtin_amdgcn_mfma_f32_16x16x32_f16(
                    kf[ni], qfh[1][kt], s1[ni], 0, 0, 0);
                s1[ni] = __builtin_amdgcn_mfma_f32_16x16x32_f16(
                    kf[ni], qfl[1][kt], s1[ni], 0, 0, 0);
            }
        }

        // --- online softmax (exp2 domain), both q-halves ---
        float mxa[2];
#pragma unroll
        for (int h = 0; h < 2; ++h) {
            const f32x4* sh = h ? s1 : s0;
            float a = fmaxf(fmaxf(sh[0][0], sh[0][1]), fmaxf(sh[0][2], sh[0][3]));
            float b = fmaxf(fmaxf(sh[1][0], sh[1][1]), fmaxf(sh[1][2], sh[1][3]));
            float c = fmaxf(fmaxf(sh[2][0], sh[2][1]), fmaxf(sh[2][2], sh[2][3]));
            float d = fmaxf(fmaxf(sh[3][0], sh[3][1]), fmaxf(sh[3][2], sh[3][3]));
            float mx = fmaxf(fmaxf(a, b), fmaxf(c, d));
            mx = fmaxf(mx, __shfl_xor(mx, 16, 64));
            mx = fmaxf(mx, __shfl_xor(mx, 32, 64));
            mxa[h] = mx;
        }
        float mnew0 = fmaxf(m0, mxa[0]);
        float mnew1 = fmaxf(m1, mxa[1]);
        if (__any(fmaxf(mxa[0] - m0, mxa[1] - m1) > 0.f)) {   // wave-uniform; skip EXACT
            float a0 = ex2(m0 - mnew0);
            float a1 = ex2(m1 - mnew1);
#pragma unroll
            for (int ni = 0; ni < 4; ++ni) { acc_o[0][ni] *= a0; acc_o[1][ni] *= a1; }
            acc_l0[0] *= a0;
            acc_l1[0] *= a1;
            m0 = mnew0;
            m1 = mnew1;
        }
#pragma unroll
        for (int ni = 0; ni < 4; ++ni) {
            uint2 u;
            u.x = pkrtz(ex2(s0[ni][0] - mnew0), ex2(s0[ni][1] - mnew0));
            u.y = pkrtz(ex2(s0[ni][2] - mnew0), ex2(s0[ni][3] - mnew0));
            *reinterpret_cast<uint2*>(&Ps[psRow0 + psX + ((ni ^ sw) * 16)]) = u;
            uint2 v;
            v.x = pkrtz(ex2(s1[ni][0] - mnew1), ex2(s1[ni][1] - mnew1));
            v.y = pkrtz(ex2(s1[ni][2] - mnew1), ex2(s1[ni][3] - mnew1));
            *reinterpret_cast<uint2*>(&Ps[psRow1 + psX + ((ni ^ sw) * 16)]) = v;
        }
        // no barrier: wave reads back only its own Ps rows

        // --- O^T += V^T.P^T ; l += 1^T.P^T (each vf feeds 2 MFMAs) ---
#pragma unroll
        for (int kt = 0; kt < 2; ++kt) {
            int pchunk = (kt * 2 + (quad >> 1)) ^ sw;
            int poff = pchunk * 16 + (((quad & 1) ^ w1) * 8);
            f16x8 pf0 = ld8h(&Ps[psRow0 + poff]);
            f16x8 pf1 = ld8h(&Ps[psRow1 + poff]);
            f16x8 vf[4];
#pragma unroll
            for (int ni = 0; ni < 4; ++ni) {
                int slot = (kt * 4 + quad) ^ (l15 & 7);
                vf[ni] = ld8h(&Vs[bb + (ni * 16 + l15) * 64 + slot * 8]);
            }
#pragma unroll
            for (int ni = 0; ni < 4; ++ni) {
                acc_o[0][ni] = __builtin_amdgcn_mfma_f32_16x16x32_f16(
                    vf[ni], pf0, acc_o[0][ni], 0, 0, 0);
                acc_o[1][ni] = __builtin_amdgcn_mfma_f32_16x16x32_f16(
                    vf[ni], pf1, acc_o[1][ni], 0, 0, 0);
            }
            acc_l0 = __builtin_amdgcn_mfma_f32_16x16x32_f16(ones, pf0, acc_l0, 0, 0, 0);
            acc_l1 = __builtin_amdgcn_mfma_f32_16x16x32_f16(ones, pf1, acc_l1, 0, 0, 0);
        }
    }

    // --- epilogue: scale 1/l, transpose O^T via Ps (same swizzle), coalesced stores ---
    const int b = bh >> 4, hh = bh & 15;
    const int echunk = quad ^ sw;
#pragma unroll
    for (int h = 0; h < 2; ++h) {
        const float inv = 1.0f / (h ? acc_l1[0] : acc_l0[0]);
        const int psRow = h ? psRow1 : psRow0;
        const f32x4* ao = acc_o[h];
#pragma unroll
        for (int ni = 0; ni < 4; ++ni) {
            uint2 u;
            u.x = pkrtn(ao[ni][0] * inv, ao[ni][1] * inv);
            u.y = pkrtn(ao[ni][2] * inv, ao[ni][3] * inv);
            *reinterpret_cast<uint2*>(&Ps[psRow + psX + ((ni ^ sw) * 16)]) = u;
        }
        const int qrow = qt * 128 + wv * 32 + h * 16 + l15;   // lane stores row q=l15
        // logical 8-el pair p lives at physical pair p^w1
        uint4 o0 = *reinterpret_cast<const uint4*>(&Ps[psRow + echunk * 16 + w1 * 8]);
        uint4 o1 = *reinterpret_cast<const uint4*>(&Ps[psRow + echunk * 16 + (1 - w1) * 8]);
        size_t outb = ((size_t)(b * SEQ + qrow)) * D_MODEL + hh * 64 + quad * 16;
        *reinterpret_cast<uint4*>(&AO[outb])     = o0;
        *reinterpret_cast<uint4*>(&AO[outb + 8]) = o1;
    }
}

// ---------------- host ----------------
extern "C" void kernel_launch(void* const* d_in, const int* in_sizes, int n_in,
                              void* d_out, int out_size, void* d_ws, size_t ws_size,
                              hipStream_t stream) {
    const float* xq  = (const float*)d_in[0];
    const float* xc  = (const float*)d_in[1];
    const float* Wq  = (const float*)d_in[2];
    const float* Wkv = (const float*)d_in[3];
    const float* Wp  = (const float*)d_in[4];
    const float* bp  = (const float*)d_in[5];
    const float* lng = (const float*)d_in[6];
    const float* lnb = (const float*)d_in[7];
    float* out = (float*)d_out;

    char* ws = (char*)d_ws;
    const size_t MB = 1 << 20;
    u16* AO     = (u16*)(ws + 0 * MB);    // 8 MB (fp16)  [xq16/xc16 slots freed]
    u16* WqT16  = (u16*)(ws + 16 * MB);   // 2 MB (fp16)
    u16* WkvT16 = (u16*)(ws + 18 * MB);   // 4 MB (fp16)
    u16* WpT16  = (u16*)(ws + 22 * MB);   // 2 MB (fp16)
    u16* Qh_h   = (u16*)(ws + 24 * MB);   // 8 MB (fp16 hi)
    u16* Qh_l   = (u16*)(ws + 32 * MB);   // 8 MB (fp16 lo)
    u16* Kh     = (u16*)(ws + 40 * MB);   // 8 MB (fp16)
    u16* VT     = (u16*)(ws + 48 * MB);   // 8 MB (fp16)

    k_prep<<<4096, 256, 0, stream>>>(Wq, Wkv, Wp, WqT16, WkvT16, WpT16);
    k_proj_f16<<<dim3(24, 32), 256, 0, stream>>>(xq, xc, WqT16, WkvT16,
                                                 lng, lnb, Qh_h, Qh_l, Kh, VT);
    k_attn<<<512, 256, 0, stream>>>(Qh_h, Qh_l, Kh, VT, AO);
    k_gemm_out<<<dim3(8, 32), 256, 0, stream>>>(AO, WpT16, bp, out);
}

// Round 10
// 231.205 us; speedup vs baseline: 1.0452x; 1.0452x over previous
//
#include <hip/hip_runtime.h>
#include <stdint.h>

#define NUM_HEADS 16
#define HEAD_DIM 64
#define D_MODEL 1024
#define SEQ 2048
#define BATCH 2

typedef unsigned short u16;
typedef _Float16 f16x8 __attribute__((ext_vector_type(8)));
typedef float f32x4 __attribute__((ext_vector_type(4)));

__device__ __forceinline__ u16 f2h(float f) {
    _Float16 h = (_Float16)f;
    return __builtin_bit_cast(u16, h);
}
__device__ __forceinline__ float h2f(u16 h) {
    return (float)__builtin_bit_cast(_Float16, h);
}
// pack two f32 -> two f16 (RTZ) as a uint32
__device__ __forceinline__ uint32_t pkrtz(float a, float b) {
    return __builtin_bit_cast(uint32_t, __builtin_amdgcn_cvt_pkrtz(a, b));
}
// pack two f32 -> two f16 round-to-nearest
__device__ __forceinline__ uint32_t pkrtn(float a, float b) {
    return (uint32_t)f2h(a) | ((uint32_t)f2h(b) << 16);
}

// raw exp2 (v_exp_f32). Q is pre-scaled by log2(e) so this IS exp().
__device__ __forceinline__ float ex2(float x) {
#if __has_builtin(__builtin_amdgcn_exp2f)
    return __builtin_amdgcn_exp2f(x);
#else
    float r;
    asm("v_exp_f32 %0, %1" : "=v"(r) : "v"(x));
    return r;
#endif
}

__device__ __forceinline__ f16x8 ld8h(const u16* p) {
    return *reinterpret_cast<const f16x8*>(p);
}

__device__ __forceinline__ void gl_lds16(const void* g, void* l) {
    __builtin_amdgcn_global_load_lds(
        (const __attribute__((address_space(1))) void*)g,
        (__attribute__((address_space(3))) void*)l,
        16, 0, 0);
}

// ---- DPP 16-lane sum (VALU pipe) ----
template <int CTRL>
__device__ __forceinline__ float dpp_mov(float x) {
    return __builtin_bit_cast(float,
        __builtin_amdgcn_update_dpp(0, __builtin_bit_cast(int, x), CTRL, 0xf, 0xf, true));
}
__device__ __forceinline__ float rowsum16(float x) {
    x += dpp_mov<0x121>(x);
    x += dpp_mov<0x122>(x);
    x += dpp_mov<0x124>(x);
    x += dpp_mov<0x128>(x);
    return x;
}

// ---------------- fused prep: cast xq,xc -> fp16 + transpose 3 weights -> fp16 ----------------
__global__ __launch_bounds__(256) void k_prep(const float* __restrict__ xq,
                                              const float* __restrict__ xc,
                                              const float* __restrict__ Wq,
                                              const float* __restrict__ Wkv,
                                              const float* __restrict__ Wp,
                                              u16* __restrict__ xq16,
                                              u16* __restrict__ xc16,
                                              u16* __restrict__ WqT16,
                                              u16* __restrict__ WkvT16,
                                              u16* __restrict__ WpT16) {
    __shared__ float tile[32][33];
    const int t = blockIdx.x;
    if (t < 8192) {
        int i = t * 256 + threadIdx.x;
        const float* src; u16* dst; int j;
        if (i < 1048576) { src = xq; dst = xq16; j = i; }
        else             { src = xc; dst = xc16; j = i - 1048576; }
        float4 v = reinterpret_cast<const float4*>(src)[j];
        ushort4 o;
        o.x = f2h(v.x); o.y = f2h(v.y); o.z = f2h(v.z); o.w = f2h(v.w);
        reinterpret_cast<ushort4*>(dst)[j] = o;
        return;
    }
    const float* W; u16* WT; int N, bi;
    if (t < 9216)       { W = Wq;  WT = WqT16;  N = 1024; bi = t - 8192; }
    else if (t < 11264) { W = Wkv; WT = WkvT16; N = 2048; bi = t - 9216; }
    else                { W = Wp;  WT = WpT16;  N = 1024; bi = t - 11264; }
    const int K = 1024;
    const int nb = N / 32;
    const int bn = (bi % nb) * 32, bk = (bi / nb) * 32;
    const int tx = threadIdx.x & 31;
    const int ty = threadIdx.x >> 5;
#pragma unroll
    for (int i = 0; i < 32; i += 8)
        tile[ty + i][tx] = W[(size_t)(bk + ty + i) * N + bn + tx];
    __syncthreads();
#pragma unroll
    for (int i = 0; i < 32; i += 8)
        WT[(size_t)(bn + ty + i) * K + bk + tx] = f2h(tile[tx][ty + i]);
}

// ---------------- fp16 GEMM mainloop, double-buffered (128M x 128N tile) ----------------
__device__ __forceinline__ void gemm_mainloop_f16(const u16* __restrict__ A,
                                                  const u16* __restrict__ Bt,
                                                  u16* As, u16* Bs,
                                                  int tileM, int tileN, int K,
                                                  f32x4 acc[4][4]) {
    const int tid = threadIdx.x;
    const int lane = tid & 63;
    const int wv = tid >> 6;
    const int wm = wv >> 1, wn = wv & 1;
    const int quad = lane >> 4, l15 = lane & 15;

    const int c0 = tid, c1 = tid + 256;
    const u16* Ap0 = A + (size_t)(tileM + (c0 >> 2)) * K + (c0 & 3) * 8;
    const u16* Ap1 = A + (size_t)(tileM + (c1 >> 2)) * K + (c1 & 3) * 8;
    const u16* Bp0 = Bt + (size_t)(tileN + (c0 >> 2)) * K + (c0 & 3) * 8;
    const u16* Bp1 = Bt + (size_t)(tileN + (c1 >> 2)) * K + (c1 & 3) * 8;

    // prologue: stage K-step 0 into buffer 0
    gl_lds16(Ap0, &As[c0 * 8]);
    gl_lds16(Ap1, &As[c1 * 8]);
    gl_lds16(Bp0, &Bs[c0 * 8]);
    gl_lds16(Bp1, &Bs[c1 * 8]);

    for (int k0 = 0; k0 < K; k0 += 32) {
        __syncthreads();
        const int cb = (k0 >> 5) & 1;
        if (k0 + 32 < K) {
            const int nbuf = cb ^ 1;
            gl_lds16(Ap0 + k0 + 32, &As[nbuf * 4096 + c0 * 8]);
            gl_lds16(Ap1 + k0 + 32, &As[nbuf * 4096 + c1 * 8]);
            gl_lds16(Bp0 + k0 + 32, &Bs[nbuf * 4096 + c0 * 8]);
            gl_lds16(Bp1 + k0 + 32, &Bs[nbuf * 4096 + c1 * 8]);
        }
        const int cbo = cb * 4096;
        f16x8 af[4], bfr[4];
#pragma unroll
        for (int mi = 0; mi < 4; ++mi)
            af[mi] = ld8h(&As[cbo + (wm * 64 + mi * 16 + l15) * 32 + quad * 8]);
#pragma unroll
        for (int ni = 0; ni < 4; ++ni)
            bfr[ni] = ld8h(&Bs[cbo + (wn * 64 + ni * 16 + l15) * 32 + quad * 8]);
#pragma unroll
        for (int mi = 0; mi < 4; ++mi)
#pragma unroll
            for (int ni = 0; ni < 4; ++ni)
                acc[mi][ni] = __builtin_amdgcn_mfma_f32_16x16x32_f16(
                    af[mi], bfr[ni], acc[mi][ni], 0, 0, 0);
    }
}

#define ACC_INIT()                                                   \
    f32x4 acc[4][4];                                                 \
    _Pragma("unroll") for (int i = 0; i < 4; ++i)                    \
        _Pragma("unroll") for (int j = 0; j < 4; ++j)                \
            acc[i][j] = (f32x4){0.f, 0.f, 0.f, 0.f};

// ---------------- fused QKV projection: Q -> LN + split-fp16, K -> LN + fp16, V -> fp16 VT.
// Epilogue bounces outputs through the (dead) As/Bs LDS so every global
// store is a coalesced dwordx4 (r7: non-attn 150.6 -> 145.6us).
__global__ __launch_bounds__(256, 2) void k_proj_f16(const u16* __restrict__ xq16,
                                                     const u16* __restrict__ xc16,
                                                     const u16* __restrict__ WqT16,
                                                     const u16* __restrict__ WkvT16,
                                                     const float* __restrict__ lng,
                                                     const float* __restrict__ lnb,
                                                     u16* __restrict__ Qh_h,
                                                     u16* __restrict__ Qh_l,
                                                     u16* __restrict__ Kh,
                                                     u16* __restrict__ VT) {
    __shared__ __align__(16) u16 As[2 * 128 * 32];
    __shared__ __align__(16) u16 Bs[2 * 128 * 32];
    const int bx = blockIdx.x;
    const int tileM = blockIdx.y * 128;
    const int tid = threadIdx.x;
    const int lane = tid & 63;
    const int wv = tid >> 6;
    const int wm = wv >> 1, wn = wv & 1;
    const int quad = lane >> 4, l15 = lane & 15;
    ACC_INIT();

    if (bx < 16) {   // Q or K: fp16 GEMM + LayerNorm
        const bool isQ = bx < 8;
        const int tileN = (bx & 7) * 128;
        const u16* Axx = isQ ? xq16 : xc16;
        const u16* Bt  = isQ ? WqT16 : WkvT16;
        // Q scale = sqrt(64) * log2(e): softmax runs in exp2 domain. K unscaled.
        const float scl = isQ ? 11.5415603294809528f : 1.0f;

        gemm_mainloop_f16(Axx, Bt, As, Bs, tileM, tileN, D_MODEL, acc);

        float gv[4], bv[4];
#pragma unroll
        for (int ni = 0; ni < 4; ++ni) { gv[ni] = lng[ni * 16 + l15]; bv[ni] = lnb[ni * 16 + l15]; }

        __syncthreads();   // all waves done with As/Bs mainloop reads
        // per-wave-private 8KB bounce region (u16[4096])
        u16* reg = (wv < 2 ? As : Bs) + (wv & 1) * 4096;
        const int h = (tileN + wn * 64) >> 6;            // uniform per wave
        const int mbase0 = tileM + wm * 64;
        const int bb = mbase0 >> 11;
        const size_t gb0 = (((size_t)bb * NUM_HEADS + h) * SEQ + (mbase0 & (SEQ - 1))) * HEAD_DIM;

#pragma unroll
        for (int mi = 0; mi < 4; ++mi) {
#pragma unroll
            for (int r = 0; r < 4; ++r) {
                float sum = 0.f, sq = 0.f;
#pragma unroll
                for (int ni = 0; ni < 4; ++ni) { float x = acc[mi][ni][r]; sum += x; sq += x * x; }
                sum = rowsum16(sum);
                sq  = rowsum16(sq);
                float mu = sum * (1.f / 64.f);
                float var = sq * (1.f / 64.f) - mu * mu;
                float rs = rsqrtf(var + 1e-5f);
                const int wrow = quad * 4 + r;
#pragma unroll
                for (int ni = 0; ni < 4; ++ni) {
                    float y = ((acc[mi][ni][r] - mu) * rs * gv[ni] + bv[ni]) * scl;
                    u16 yh = f2h(y);
                    reg[wrow * 64 + ni * 16 + l15] = yh;
                    if (isQ) reg[1024 + wrow * 64 + ni * 16 + l15] = f2h(y - h2f(yh));
                }
            }
            // coalesced readback: 2 rounds x 8 rows x 128B = 1KB contiguous/instr
            const size_t gmi = gb0 + (size_t)mi * 16 * 64;
#pragma unroll
            for (int p = 0; p < 2; ++p) {
                const int row = p * 8 + (lane >> 3);
                const int off = (lane & 7) * 8;
                uint4 vh = *reinterpret_cast<const uint4*>(&reg[row * 64 + off]);
                if (isQ) {
                    uint4 vl = *reinterpret_cast<const uint4*>(&reg[1024 + row * 64 + off]);
                    *reinterpret_cast<uint4*>(&Qh_h[gmi + row * 64 + off]) = vh;
                    *reinterpret_cast<uint4*>(&Qh_l[gmi + row * 64 + off]) = vl;
                } else {
                    *reinterpret_cast<uint4*>(&Kh[gmi + row * 64 + off]) = vh;
                }
            }
        }
    } else {         // V: fp16 GEMM, store fp16 transposed (d-major)
        const int tileN = D_MODEL + (bx - 16) * 128;
        gemm_mainloop_f16(xc16, WkvT16, As, Bs, tileM, tileN, D_MODEL, acc);

        __syncthreads();   // all waves done with As/Bs mainloop reads
        u16* reg = (wv < 2 ? As : Bs) + (wv & 1) * 4096;   // 8KB: [64 d][64 n], chunk-XOR
        // bounce in: per (mi,ni) one 8B LDS write (4 n-values); chunk-pair XOR'd by d
#pragma unroll
        for (int mi = 0; mi < 4; ++mi) {
#pragma unroll
            for (int ni = 0; ni < 4; ++ni) {
                const int d = ni * 16 + l15;
                const int pc = (mi * 2 + (quad >> 1)) ^ (d & 7);
                ushort4 o;
                o.x = f2h(acc[mi][ni][0]);
                o.y = f2h(acc[mi][ni][1]);
                o.z = f2h(acc[mi][ni][2]);
                o.w = f2h(acc[mi][ni][3]);
                *reinterpret_cast<ushort4*>(&reg[d * 64 + pc * 8 + (quad & 1) * 4]) = o;
            }
        }
        const int h = (tileN + wn * 64 - D_MODEL) >> 6;    // uniform per wave
        const int m0 = tileM + wm * 64;
        const int bb = m0 >> 11, n0 = m0 & (SEQ - 1);
        const size_t vbase = (((size_t)bb * NUM_HEADS + h) * HEAD_DIM) * SEQ + n0;
        // readback: 8 rounds x 8 d-rows x 128B transactions
#pragma unroll
        for (int p = 0; p < 8; ++p) {
            const int d = p * 8 + (lane >> 3);
            const int c = lane & 7;
            uint4 v = *reinterpret_cast<const uint4*>(&reg[d * 64 + ((c ^ (d & 7)) * 8)]);
            *reinterpret_cast<uint4*>(&VT[vbase + (size_t)d * SEQ + c * 8]) = v;
        }
    }
}

// ---------------- output projection + bias -> out fp32 (fp16 GEMM) ----------------
__global__ __launch_bounds__(256, 2) void k_gemm_out(const u16* __restrict__ A,
                                                     const u16* __restrict__ Bt,
                                                     const float* __restrict__ bp,
                                                     float* __restrict__ out) {
    __shared__ __align__(16) u16 As[2 * 128 * 32];
    __shared__ __align__(16) u16 Bs[2 * 128 * 32];
    const int tileM = blockIdx.y * 128, tileN = blockIdx.x * 128;
    const int tid = threadIdx.x;
    const int lane = tid & 63;
    const int wv = tid >> 6;
    const int wm = wv >> 1, wn = wv & 1;
    const int quad = lane >> 4, l15 = lane & 15;
    ACC_INIT();
    gemm_mainloop_f16(A, Bt, As, Bs, tileM, tileN, D_MODEL, acc);

    float bpv[4];
#pragma unroll
    for (int ni = 0; ni < 4; ++ni) bpv[ni] = bp[tileN + wn * 64 + ni * 16 + l15];
#pragma unroll
    for (int mi = 0; mi < 4; ++mi) {
#pragma unroll
        for (int r = 0; r < 4; ++r) {
            int m = tileM + wm * 64 + mi * 16 + quad * 4 + r;
#pragma unroll
            for (int ni = 0; ni < 4; ++ni) {
                int colg = tileN + wn * 64 + ni * 16 + l15;
                out[(size_t)m * D_MODEL + colg] = acc[mi][ni][r] + bpv[ni];
            }
        }
    }
}

// ---------------- flash attention v10 (measured best: 82.7-84us): 32q/wave,
// block covers 128 q-rows, grid 512. VGPR 116 natural (NO forced bound --
// r7's __launch_bounds__(256,4) collapsed allocation to 64 VGPR and spilled
// 41MB/dispatch to scratch: 124us). LDS 48KB -> 3 blocks/CU.
__global__ __launch_bounds__(256) void k_attn(const u16* __restrict__ Qh_h,
                                              const u16* __restrict__ Qh_l,
                                              const u16* __restrict__ Kh,
                                              const u16* __restrict__ VT,
                                              u16* __restrict__ AO) {
    __shared__ __align__(16) u16 Ks[2 * 64 * 64];   // fp16, double-buffered
    __shared__ __align__(16) u16 Vs[2 * 64 * 64];   // fp16, double-buffered
    __shared__ __align__(16) u16 Ps[128 * 64];      // fp16, chunk+unit XOR swizzled

    const int tid = threadIdx.x;
    const int lane = tid & 63;
    const int wv = tid >> 6;               // wave owns q cols [wv*32, wv*32+32)
    const int quad = lane >> 4, l15 = lane & 15;
    const int sw = l15 & 3;                // Ps chunk XOR key
    const int w1 = (l15 >> 2) & 1;         // Ps 8B-unit XOR key (bank spread)
    const int id = blockIdx.x;             // 0..511
    const int bh = (id & 7) | (((id >> 7) & 3) << 3);  // bh&7 == XCD id
    const int qt = (id >> 3) & 15;         // q-tile of 128 rows

    const size_t bh_off = (size_t)bh * SEQ * HEAD_DIM;
    const u16* Vbh = VT + (size_t)bh * HEAD_DIM * SEQ;

    // Q fragments (B operand), 2 q-halves x 2 k-chunks, split fp16
    f16x8 qfh[2][2], qfl[2][2];
#pragma unroll
    for (int h = 0; h < 2; ++h)
#pragma unroll
        for (int kt = 0; kt < 2; ++kt) {
            size_t off = bh_off +
                (size_t)(qt * 128 + wv * 32 + h * 16 + l15) * HEAD_DIM + kt * 32 + quad * 8;
            qfh[h][kt] = ld8h(Qh_h + off);
            qfl[h][kt] = ld8h(Qh_l + off);
        }

    // all-ones A fragment for the row-sum MFMA (l = sum_k P[k][q])
    f16x8 ones;
#pragma unroll
    for (int i = 0; i < 8; ++i) ones[i] = (_Float16)1.0f;

    // staging pointers (wave stages tile rows [wv*16, wv*16+16))
    const int rr = lane >> 3;
    const int ss = lane & 7;
    const int cc = ss ^ rr;                // XOR chunk swizzle on global source
    const int row0 = wv * 16 + rr;
    const u16* k0 = Kh + bh_off + (size_t)row0 * HEAD_DIM + cc * 8;
    const u16* v0 = Vbh + (size_t)row0 * SEQ + cc * 8;
    const int ldsW = (wv * 16) * 64;       // wave's row base within a buffer

    f32x4 acc_o[2][4];                     // O^T[d][q] per q-half
    f32x4 acc_l0 = (f32x4){0.f, 0.f, 0.f, 0.f};   // only [0] live
    f32x4 acc_l1 = (f32x4){0.f, 0.f, 0.f, 0.f};
    float m0 = -3.0e38f, m1 = -3.0e38f;
#pragma unroll
    for (int h = 0; h < 2; ++h)
#pragma unroll
        for (int ni = 0; ni < 4; ++ni) acc_o[h][ni] = (f32x4){0.f, 0.f, 0.f, 0.f};

    // prologue: stage tile 0 into buffer 0
    gl_lds16(k0,                &Ks[ldsW]);
    gl_lds16(k0 + 8 * HEAD_DIM, &Ks[ldsW + 8 * 64]);
    gl_lds16(v0,                &Vs[ldsW]);
    gl_lds16(v0 + 8 * SEQ,      &Vs[ldsW + 8 * 64]);

    const int psRow0 = (wv * 32 + l15) * 64;         // q-half 0 row (wave-private)
    const int psRow1 = psRow0 + 16 * 64;             // q-half 1 row
    const int psX = (quad ^ (w1 << 1)) * 4;          // unit-XOR'd write offset

    for (int j = 0; j < SEQ / 64; ++j) {
        __syncthreads();   // drains vmcnt -> buf[j&1] ready; all waves done with buf[(j+1)&1]
        if (j + 1 < SEQ / 64) {
            const int nb = (j + 1) & 1;
            const size_t ko = (size_t)(j + 1) * 64 * HEAD_DIM;
            const int vo = (j + 1) * 64;
            gl_lds16(k0 + ko,                &Ks[nb * 4096 + ldsW]);
            gl_lds16(k0 + ko + 8 * HEAD_DIM, &Ks[nb * 4096 + ldsW + 8 * 64]);
            gl_lds16(v0 + vo,                &Vs[nb * 4096 + ldsW]);
            gl_lds16(v0 + vo + 8 * SEQ,      &Vs[nb * 4096 + ldsW + 8 * 64]);
        }
        const int bb = (j & 1) * 4096;

        // --- S^T = K.Q^T (64 keys x 32 q per wave): each kf feeds 4 MFMAs ---
        f32x4 s0[4], s1[4];   // per q-half: col q=l15, row key=ni*16+quad*4+r
#pragma unroll
        for (int ni = 0; ni < 4; ++ni) {
            s0[ni] = (f32x4){0.f, 0.f, 0.f, 0.f};
            s1[ni] = (f32x4){0.f, 0.f, 0.f, 0.f};
        }
#pragma unroll
        for (int kt = 0; kt < 2; ++kt) {
            f16x8 kf[4];
#pragma unroll
            for (int ni = 0; ni < 4; ++ni) {
                int slot = (kt * 4 + quad) ^ (l15 & 7);
                kf[ni] = ld8h(&Ks[bb + (ni * 16 + l15) * 64 + slot * 8]);
            }
#pragma unroll
            for (int ni = 0; ni < 4; ++ni) {
                s0[ni] = __builtin_amdgcn_mfma_f32_16x16x32_f16(
                    kf[ni], qfh[0][kt], s0[ni], 0, 0, 0);
                s0[ni] = __builtin_amdgcn_mfma_f32_16x16x32_f16(
                    kf[ni], qfl[0][kt], s0[ni], 0, 0, 0);
                s1[ni] = __builtin_amdgcn_mfma_f32_16x16x32_f16(
                    kf[ni], qfh[1][kt], s1[ni], 0, 0, 0);
                s1[ni] = __builtin_amdgcn_mfma_f32_16x16x32_f16(
                    kf[ni], qfl[1][kt], s1[ni], 0, 0, 0);
            }
        }

        // --- online softmax (exp2 domain), both q-halves ---
        float mxa[2];
#pragma unroll
        for (int h = 0; h < 2; ++h) {
            const f32x4* sh = h ? s1 : s0;
            float a = fmaxf(fmaxf(sh[0][0], sh[0][1]), fmaxf(sh[0][2], sh[0][3]));
            float b = fmaxf(fmaxf(sh[1][0], sh[1][1]), fmaxf(sh[1][2], sh[1][3]));
            float c = fmaxf(fmaxf(sh[2][0], sh[2][1]), fmaxf(sh[2][2], sh[2][3]));
            float d = fmaxf(fmaxf(sh[3][0], sh[3][1]), fmaxf(sh[3][2], sh[3][3]));
            float mx = fmaxf(fmaxf(a, b), fmaxf(c, d));
            mx = fmaxf(mx, __shfl_xor(mx, 16, 64));
            mx = fmaxf(mx, __shfl_xor(mx, 32, 64));
            mxa[h] = mx;
        }
        float mnew0 = fmaxf(m0, mxa[0]);
        float mnew1 = fmaxf(m1, mxa[1]);
        if (__any(fmaxf(mxa[0] - m0, mxa[1] - m1) > 0.f)) {   // wave-uniform; skip EXACT
            float a0 = ex2(m0 - mnew0);
            float a1 = ex2(m1 - mnew1);
#pragma unroll
            for (int ni = 0; ni < 4; ++ni) { acc_o[0][ni] *= a0; acc_o[1][ni] *= a1; }
            acc_l0[0] *= a0;
            acc_l1[0] *= a1;
            m0 = mnew0;
            m1 = mnew1;
        }
#pragma unroll
        for (int ni = 0; ni < 4; ++ni) {
            uint2 u;
            u.x = pkrtz(ex2(s0[ni][0] - mnew0), ex2(s0[ni][1] - mnew0));
            u.y = pkrtz(ex2(s0[ni][2] - mnew0), ex2(s0[ni][3] - mnew0));
            *reinterpret_cast<uint2*>(&Ps[psRow0 + psX + ((ni ^ sw) * 16)]) = u;
            uint2 v;
            v.x = pkrtz(ex2(s1[ni][0] - mnew1), ex2(s1[ni][1] - mnew1));
            v.y = pkrtz(ex2(s1[ni][2] - mnew1), ex2(s1[ni][3] - mnew1));
            *reinterpret_cast<uint2*>(&Ps[psRow1 + psX + ((ni ^ sw) * 16)]) = v;
        }
        // no barrier: wave reads back only its own Ps rows

        // --- O^T += V^T.P^T ; l += 1^T.P^T (each vf feeds 2 MFMAs) ---
#pragma unroll
        for (int kt = 0; kt < 2; ++kt) {
            int pchunk = (kt * 2 + (quad >> 1)) ^ sw;
            int poff = pchunk * 16 + (((quad & 1) ^ w1) * 8);
            f16x8 pf0 = ld8h(&Ps[psRow0 + poff]);
            f16x8 pf1 = ld8h(&Ps[psRow1 + poff]);
            f16x8 vf[4];
#pragma unroll
            for (int ni = 0; ni < 4; ++ni) {
                int slot = (kt * 4 + quad) ^ (l15 & 7);
                vf[ni] = ld8h(&Vs[bb + (ni * 16 + l15) * 64 + slot * 8]);
            }
#pragma unroll
            for (int ni = 0; ni < 4; ++ni) {
                acc_o[0][ni] = __builtin_amdgcn_mfma_f32_16x16x32_f16(
                    vf[ni], pf0, acc_o[0][ni], 0, 0, 0);
                acc_o[1][ni] = __builtin_amdgcn_mfma_f32_16x16x32_f16(
                    vf[ni], pf1, acc_o[1][ni], 0, 0, 0);
            }
            acc_l0 = __builtin_amdgcn_mfma_f32_16x16x32_f16(ones, pf0, acc_l0, 0, 0, 0);
            acc_l1 = __builtin_amdgcn_mfma_f32_16x16x32_f16(ones, pf1, acc_l1, 0, 0, 0);
        }
    }

    // --- epilogue: scale 1/l, transpose O^T via Ps (same swizzle), coalesced stores ---
    const int b = bh >> 4, hh = bh & 15;
    const int echunk = quad ^ sw;
#pragma unroll
    for (int h = 0; h < 2; ++h) {
        const float inv = 1.0f / (h ? acc_l1[0] : acc_l0[0]);
        const int psRow = h ? psRow1 : psRow0;
        const f32x4* ao = acc_o[h];
#pragma unroll
        for (int ni = 0; ni < 4; ++ni) {
            uint2 u;
            u.x = pkrtn(ao[ni][0] * inv, ao[ni][1] * inv);
            u.y = pkrtn(ao[ni][2] * inv, ao[ni][3] * inv);
            *reinterpret_cast<uint2*>(&Ps[psRow + psX + ((ni ^ sw) * 16)]) = u;
        }
        const int qrow = qt * 128 + wv * 32 + h * 16 + l15;   // lane stores row q=l15
        // logical 8-el pair p lives at physical pair p^w1
        uint4 o0 = *reinterpret_cast<const uint4*>(&Ps[psRow + echunk * 16 + w1 * 8]);
        uint4 o1 = *reinterpret_cast<const uint4*>(&Ps[psRow + echunk * 16 + (1 - w1) * 8]);
        size_t outb = ((size_t)(b * SEQ + qrow)) * D_MODEL + hh * 64 + quad * 16;
        *reinterpret_cast<uint4*>(&AO[outb])     = o0;
        *reinterpret_cast<uint4*>(&AO[outb + 8]) = o1;
    }
}

// ---------------- host ----------------
extern "C" void kernel_launch(void* const* d_in, const int* in_sizes, int n_in,
                              void* d_out, int out_size, void* d_ws, size_t ws_size,
                              hipStream_t stream) {
    const float* xq  = (const float*)d_in[0];
    const float* xc  = (const float*)d_in[1];
    const float* Wq  = (const float*)d_in[2];
    const float* Wkv = (const float*)d_in[3];
    const float* Wp  = (const float*)d_in[4];
    const float* bp  = (const float*)d_in[5];
    const float* lng = (const float*)d_in[6];
    const float* lnb = (const float*)d_in[7];
    float* out = (float*)d_out;

    char* ws = (char*)d_ws;
    const size_t MB = 1 << 20;
    u16* xq16   = (u16*)(ws + 0 * MB);    // 8 MB (fp16)
    u16* xc16   = (u16*)(ws + 8 * MB);    // 8 MB (fp16)
    u16* WqT16  = (u16*)(ws + 16 * MB);   // 2 MB (fp16)
    u16* WkvT16 = (u16*)(ws + 18 * MB);   // 4 MB (fp16)
    u16* WpT16  = (u16*)(ws + 22 * MB);   // 2 MB (fp16)
    u16* Qh_h   = (u16*)(ws + 24 * MB);   // 8 MB (fp16 hi)
    u16* Qh_l   = (u16*)(ws + 32 * MB);   // 8 MB (fp16 lo)
    u16* Kh     = (u16*)(ws + 40 * MB);   // 8 MB (fp16)
    u16* VT     = (u16*)(ws + 48 * MB);   // 8 MB (fp16)
    u16* AO     = xq16;   // alias: xq16 dead after k_proj_f16

    k_prep<<<12288, 256, 0, stream>>>(xq, xc, Wq, Wkv, Wp,
                                      xq16, xc16, WqT16, WkvT16, WpT16);
    k_proj_f16<<<dim3(24, 32), 256, 0, stream>>>(xq16, xc16, WqT16, WkvT16,
                                                 lng, lnb, Qh_h, Qh_l, Kh, VT);
    k_attn<<<512, 256, 0, stream>>>(Qh_h, Qh_l, Kh, VT, AO);
    k_gemm_out<<<dim3(8, 32), 256, 0, stream>>>(AO, WpT16, bp, out);
}